// Round 4
// baseline (236.529 us; speedup 1.0000x reference)
//
#include <hip/hip_runtime.h>
#include <stdint.h>

#define NB 16
#define NC 512
#define NS 1024
#define NR 32

typedef unsigned short u16;
typedef unsigned int u32;

typedef __attribute__((ext_vector_type(8))) short short8;
typedef __attribute__((ext_vector_type(4))) float f32x4;

__device__ __forceinline__ float bf2f(u16 u) {
    union { u32 i; float f; } c; c.i = ((u32)u) << 16; return c.f;
}
__device__ __forceinline__ u16 f2bf(float f) {
    union { float f; u32 i; } c; c.f = f;
    u32 r = (c.i + 0x7FFFu + ((c.i >> 16) & 1u)) >> 16;
    return (u16)r;
}
__device__ __forceinline__ float sigm(float x) {
    return 1.0f / (1.0f + __expf(-x));
}

// ------- fused: spatial mean (blocks 0..8191) + bf16 convert (8192..12287)
__global__ void k_mean_cvt(const float* __restrict__ x, float* __restrict__ sm,
                           const float* __restrict__ g, const float* __restrict__ dw,
                           u16* __restrict__ gb, u16* __restrict__ dwb) {
    const int t = threadIdx.x;                  // 256
    if (blockIdx.x < NB * NC) {
        const int row = blockIdx.x;             // b*NC + c
        const float4* xr = (const float4*)(x + (long)row * NS);
        float4 v = xr[t];
        float p = v.x + v.y + v.z + v.w;
        for (int off = 32; off; off >>= 1) p += __shfl_down(p, off);
        __shared__ float red[4];
        if ((t & 63) == 0) red[t >> 6] = p;
        __syncthreads();
        if (t == 0) sm[row] = (red[0] + red[1] + red[2] + red[3]) * (1.0f / 1024.0f);
    } else {
        const int i = (blockIdx.x - NB * NC) * 256 + t;
        gb[i] = f2bf(g[i]);                      // 4096 blocks => exactly 1048576
        if (i < 524288) dwb[i] = f2bf(dw[i]);
    }
}

// ---------------- SE MLP: y = sigmoid(relu(s W1^T + b1) W2^T + b2) ------
__global__ void k_se(const float* __restrict__ sm, const float* __restrict__ w1,
                     const float* __restrict__ b1, const float* __restrict__ w2,
                     const float* __restrict__ b2, float* __restrict__ y) {
    const int b = blockIdx.x;
    __shared__ float s_s[NC];
    __shared__ float s_y1[NR];
    const int t = threadIdx.x;                  // 256
    s_s[t] = sm[b * NC + t];
    s_s[t + 256] = sm[b * NC + t + 256];
    __syncthreads();
    if (t < NR) {
        float acc = b1[t];
        for (int c = 0; c < NC; ++c) acc += s_s[c] * w1[t * NC + c];
        s_y1[t] = fmaxf(acc, 0.0f);
    }
    __syncthreads();
    for (int i = 0; i < 2; ++i) {
        int c = t + i * 256;
        float acc = b2[c];
#pragma unroll
        for (int r = 0; r < NR; ++r) acc += s_y1[r] * w2[c * NR + r];
        y[b * NC + c] = 1.0f / (1.0f + expf(-acc));
    }
}

// out32 = x*y -> bf16 [c,s] (o32), [s,c] (o32t), and sigmoid in [s,c] (sig_t)
__global__ void k_scale(const float* __restrict__ x, const float* __restrict__ y,
                        u16* __restrict__ o32, u16* __restrict__ o32t,
                        u16* __restrict__ sig_t) {
    const int b = blockIdx.z;
    const int c0 = blockIdx.y * 32;
    const int s0 = blockIdx.x * 32;
    const int tx = threadIdx.x & 31, ty = threadIdx.x >> 5;  // 32 x 8
    __shared__ float tile[32][33];
    const float* xb = x + (long)b * NC * NS;
#pragma unroll
    for (int it = 0; it < 4; ++it) {
        int c = c0 + ty + it * 8;
        float v = xb[(long)c * NS + s0 + tx] * y[b * NC + c];
        tile[ty + it * 8][tx] = v;
        o32[((long)b * NC + c) * NS + s0 + tx] = f2bf(v);
    }
    __syncthreads();
#pragma unroll
    for (int it = 0; it < 4; ++it) {
        int sr = ty + it * 8;
        float tv = tile[tx][sr];
        long idx = ((long)b * NS + (s0 + sr)) * NC + c0 + tx;
        o32t[idx] = f2bf(tv);
        sig_t[idx] = f2bf(sigm(tv));
    }
}

// ---------------- bf16 MFMA GEMM body: 128x128 tile, 4 waves ------------
__device__ __forceinline__ void st_out(float* p, float v) { *p = v; }
__device__ __forceinline__ void st_out(u16* p, float v) { *p = f2bf(v); }

template <typename OT>
__device__ __forceinline__
void gemm_body(const u16* __restrict__ Ab, const u16* __restrict__ Bb,
               OT* __restrict__ Cb, int m0, int n0, int N, int K,
               u16* As, u16* Bs) {
    const int tid = threadIdx.x;
    const int lane = tid & 63, wave = tid >> 6;
    const int wm = (wave >> 1) * 64, wn = (wave & 1) * 64;
    f32x4 acc[4][4];
#pragma unroll
    for (int i = 0; i < 4; ++i)
#pragma unroll
        for (int j = 0; j < 4; ++j) acc[i][j] = (f32x4){0.f, 0.f, 0.f, 0.f};

    int mrow[4], kcol[4];
#pragma unroll
    for (int q = 0; q < 4; ++q) {
        int eoff = wave * 2048 + q * 512 + lane * 8;   // element offset in 128x64 tile
        mrow[q] = eoff >> 6;
        kcol[q] = eoff & 63;
    }

    for (int k0 = 0; k0 < K; k0 += 64) {
#pragma unroll
        for (int q = 0; q < 4; ++q) {
            const u16* ga = Ab + (long)(m0 + mrow[q]) * K + (k0 + kcol[q]);
            __builtin_amdgcn_global_load_lds(
                (const __attribute__((address_space(1))) u32*)ga,
                (__attribute__((address_space(3))) u32*)&As[wave * 2048 + q * 512], 16, 0, 0);
            const u16* gb = Bb + (long)(n0 + mrow[q]) * K + (k0 + kcol[q]);
            __builtin_amdgcn_global_load_lds(
                (const __attribute__((address_space(1))) u32*)gb,
                (__attribute__((address_space(3))) u32*)&Bs[wave * 2048 + q * 512], 16, 0, 0);
        }
        __syncthreads();
#pragma unroll
        for (int kk = 0; kk < 64; kk += 32) {
            const int kidx = kk + ((lane >> 4) << 3);
            short8 af[4], bfr[4];
#pragma unroll
            for (int i = 0; i < 4; ++i)
                af[i] = *(const short8*)&As[(wm + i * 16 + (lane & 15)) * 64 + kidx];
#pragma unroll
            for (int j = 0; j < 4; ++j)
                bfr[j] = *(const short8*)&Bs[(wn + j * 16 + (lane & 15)) * 64 + kidx];
#pragma unroll
            for (int i = 0; i < 4; ++i)
#pragma unroll
                for (int j = 0; j < 4; ++j)
                    acc[i][j] = __builtin_amdgcn_mfma_f32_16x16x32_bf16(af[i], bfr[j], acc[i][j], 0, 0, 0);
        }
        __syncthreads();
    }
    const int col = lane & 15, rq = (lane >> 4) * 4;
#pragma unroll
    for (int i = 0; i < 4; ++i)
#pragma unroll
        for (int j = 0; j < 4; ++j)
#pragma unroll
            for (int r = 0; r < 4; ++r) {
                int row = m0 + wm + i * 16 + rq + r;
                int ncol = n0 + wn + j * 16 + col;
                st_out(&Cb[(long)row * N + ncol], acc[i][j][r]);
            }
}

// ---- fused dispatch: blocks 0..511 = gemm1 (gus GEMM), 512..4607 = attn ----
// gemm1: G[p,ch] = sum_s gus[p,s]*out32[ch,s]; M=1024 N=512 K=1024
// attn : patch self-attention, 4 positions/block, LDS-shared neighbor rows
__global__ __launch_bounds__(256)
void k_gemm1_attn(const u16* __restrict__ gusbf, const u16* __restrict__ o32,
                  u16* __restrict__ gbuf, const u16* __restrict__ sig_t,
                  const u16* __restrict__ o32t, u16* __restrict__ g2) {
    extern __shared__ __align__(16) char dsm[];
    if (blockIdx.x < 512) {
        const int gx = blockIdx.x;
        const int b = gx >> 5;
        const int m0 = ((gx >> 2) & 7) * 128;
        const int n0 = (gx & 3) * 128;
        u16* As = (u16*)dsm;
        u16* Bs = As + 128 * 64;
        gemm_body<u16>(gusbf, o32 + (long)b * NC * NS, gbuf + (long)b * NC * NS,
                       m0, n0, 512, 1024, As, Bs);
        return;
    }
    // ---------------- attention path ----------------
    const int id = blockIdx.x - 512;
    const int bx = id & 255;
    const int b = id >> 8;
    const int wave = threadIdx.x >> 6, lane = threadIdx.x & 63;
    const int tid = threadIdx.x;
    const int y0 = bx >> 3;
    const int xbase = (bx & 7) * 4;
    const long base = (long)b * NS * NC;
    u16* smem = (u16*)dsm;                        // [arr(2)][pair(18)][512]

#pragma unroll
    for (int r = 0; r < 9; ++r) {
        int idx = r * 256 + tid;
        int pair = idx >> 7;                      // 0..17
        int rem = idx & 127;
        int arr = rem >> 6;                       // 0=sig, 1=raw
        int ch0 = (rem & 63) * 8;
        int yy = y0 + pair / 6 - 1;
        int xx = xbase + pair % 6 - 1;
        short8 v;
        if (yy >= 0 && yy < 32 && xx >= 0 && xx < 32) {
            long roff = base + (long)(yy * 32 + xx) * NC + ch0;
            v = arr ? *(const short8*)&o32t[roff] : *(const short8*)&sig_t[roff];
        } else {
            v = (short8){0, 0, 0, 0, 0, 0, 0, 0};
        }
        *(short8*)&smem[(arr * 18 + pair) * NC + ch0] = v;
    }
    __syncthreads();

    const int coff = lane * 8;
    short8 csv = *(const short8*)&smem[(6 + wave + 1) * NC + coff];
    float sc[8];
#pragma unroll
    for (int j = 0; j < 8; ++j) sc[j] = bf2f((u16)csv[j]);

    float part[9];
#pragma unroll
    for (int k = 0; k < 9; ++k) {
        int pair = (k / 3) * 6 + wave + k % 3;
        short8 sv = *(const short8*)&smem[pair * NC + coff];
        float p = 0.f;
#pragma unroll
        for (int j = 0; j < 8; ++j) p += sc[j] * bf2f((u16)sv[j]);
        part[k] = p;
    }
#pragma unroll
    for (int k = 0; k < 9; ++k)
        for (int off = 32; off; off >>= 1) part[k] += __shfl_down(part[k], off);

    if (lane == 0) {
        float mx = -1e30f;
#pragma unroll
        for (int k = 0; k < 9; ++k) { part[k] *= (1.0f / 512.0f); mx = fmaxf(mx, part[k]); }
        float sum = 0.f;
#pragma unroll
        for (int k = 0; k < 9; ++k) { part[k] = __expf(part[k] - mx); sum += part[k]; }
        float inv = 1.0f / sum;
#pragma unroll
        for (int k = 0; k < 9; ++k) part[k] *= inv;
    }
    float g[8] = {0.f, 0.f, 0.f, 0.f, 0.f, 0.f, 0.f, 0.f};
#pragma unroll
    for (int k = 0; k < 9; ++k) {
        float a = __shfl(part[k], 0);
        int pair = (k / 3) * 6 + wave + k % 3;
        short8 rv = *(const short8*)&smem[(18 + pair) * NC + coff];
#pragma unroll
        for (int j = 0; j < 8; ++j) g[j] += a * bf2f((u16)rv[j]);
    }
    short8 ov;
#pragma unroll
    for (int j = 0; j < 8; ++j) ov[j] = (short)f2bf(g[j]);
    const int s = y0 * 32 + xbase + wave;
    *(short8*)&g2[base + (long)s * NC + coff] = ov;
}

// ---------------- standalone GEMM (gemm2), 128x128 ----------------------
template <typename OT>
__global__ __launch_bounds__(256)
void gemm_bt(const u16* __restrict__ A, const u16* __restrict__ Bt, OT* __restrict__ Co,
             int M, int N, int K, long batA, long batB, long batC) {
    const int b = blockIdx.z;
    __shared__ __align__(16) u16 As[128 * 64];
    __shared__ __align__(16) u16 Bs[128 * 64];
    gemm_body<OT>(A + (long)b * batA, Bt + (long)b * batB, Co + (long)b * batC,
                  blockIdx.y * 128, blockIdx.x * 128, N, K, As, Bs);
}

// ------- catT[b][s][i] = cat[b][i][s]  (i<512: gbuf flat, else g2 flat) --
__global__ void k_tr(const u16* __restrict__ g, const u16* __restrict__ g2,
                     u16* __restrict__ ct) {
    const int b = blockIdx.z;
    const int i0 = blockIdx.y * 32, s0 = blockIdx.x * 32;
    const int tx = threadIdx.x & 31, ty = threadIdx.x >> 5;
    __shared__ u16 tile[32][33];
    const u16* src = (i0 < 512) ? (g + (long)b * 524288 + (long)i0 * 1024)
                                : (g2 + (long)b * 524288 + (long)(i0 - 512) * 1024);
#pragma unroll
    for (int it = 0; it < 4; ++it) {
        int il = ty + it * 8;
        tile[il][tx] = src[(long)il * 1024 + s0 + tx];
    }
    __syncthreads();
#pragma unroll
    for (int it = 0; it < 4; ++it) {
        int sl = ty + it * 8;
        ct[(long)b * 1048576 + (long)(s0 + sl) * 1024 + i0 + tx] = tile[tx][sl];
    }
}

// -------- InstanceNorm over s (1024) + LeakyReLU(0.2), per (b,o) row -----
__global__ void k_norm(const float* __restrict__ z, float* __restrict__ out) {
    const int row = blockIdx.x;                 // b*NC + o
    const float4* zr = (const float4*)(z + (long)row * NS);
    const int t = threadIdx.x;
    float4 v = zr[t];
    float sm = v.x + v.y + v.z + v.w;
    float sq = v.x * v.x + v.y * v.y + v.z * v.z + v.w * v.w;
    for (int off = 32; off; off >>= 1) { sm += __shfl_down(sm, off); sq += __shfl_down(sq, off); }
    __shared__ float rs[4], rq2[4];
    if ((t & 63) == 0) { rs[t >> 6] = sm; rq2[t >> 6] = sq; }
    __syncthreads();
    float tot = rs[0] + rs[1] + rs[2] + rs[3];
    float totq = rq2[0] + rq2[1] + rq2[2] + rq2[3];
    float mu = tot * (1.0f / 1024.0f);
    float var = totq * (1.0f / 1024.0f) - mu * mu;
    float sc = rsqrtf(var + 1e-5f);
    float4 o;
    float a;
    a = (v.x - mu) * sc; o.x = (a >= 0.f) ? a : 0.2f * a;
    a = (v.y - mu) * sc; o.y = (a >= 0.f) ? a : 0.2f * a;
    a = (v.z - mu) * sc; o.z = (a >= 0.f) ? a : 0.2f * a;
    a = (v.w - mu) * sc; o.w = (a >= 0.f) ? a : 0.2f * a;
    ((float4*)(out + (long)row * NS))[t] = o;
}

extern "C" void kernel_launch(void* const* d_in, const int* in_sizes, int n_in,
                              void* d_out, int out_size, void* d_ws, size_t ws_size,
                              hipStream_t stream) {
    const float* x   = (const float*)d_in[0];
    const float* w1  = (const float*)d_in[1];
    const float* b1  = (const float*)d_in[2];
    const float* w2  = (const float*)d_in[3];
    const float* b2  = (const float*)d_in[4];
    const float* dw  = (const float*)d_in[5];
    const float* gus = (const float*)d_in[6];
    float* out = (float*)d_out;
    char* ws = (char*)d_ws;

    // workspace layout (67.1 MB, region A/B overlays)
    float* sm_buf = (float*)(ws + 0);                    // 32 KB
    float* y_buf  = (float*)(ws + 32768);                // 32 KB
    u16* gusbf    = (u16*)(ws + 65536);                  // 2 MB
    u16* dwbf     = (u16*)(ws + 2162688);                // 1 MB
    char* regA    = ws + 3211264;                        // 32 MB region A
    u16* o32      = (u16*)regA;                          //   out32 bf16 [b][c][s]
    u16* o32t     = (u16*)(regA + 16777216);             //   out32 bf16 [b][s][c]
    u16* catT     = (u16*)regA;                          //   reuse A: catT [b][s][i]
    char* regB    = ws + 36765696;                       // 32 MB region B
    u16* sig_t    = (u16*)regB;                          //   sigmoid(out32) [b][s][c] (dies in fused kernel)
    u16* gbuf     = (u16*)regB;                          //   gus_out flat bf16 — NOTE: written by same fused kernel
    u16* g2b      = (u16*)(regB + 16777216);             //   out_csa flat bf16
    float* Z      = (float*)regB;                        //   reuse B: z fp32

    // CAREFUL: gbuf overlays sig_t, but the fused kernel both reads sig_t (attn)
    // and writes gbuf (gemm1). Move gbuf to a distinct slot to avoid the race:
    u16* gbuf_safe = (u16*)(ws + 3211264 + 33554432);    // == regB start? no.
    (void)gbuf; (void)gbuf_safe;
    // Layout fix: put gbuf after g2b inside region B is impossible (region B is
    // 32 MB = sig_t(16) + g2b(16)). Use tail space after region B instead:
    u16* gbuf2 = (u16*)(ws + 36765696 + 33554432);       // 16 MB after region B

    k_mean_cvt<<<dim3(NB * NC + 4096), dim3(256), 0, stream>>>(x, sm_buf, gus, dw, gusbf, dwbf);
    k_se<<<dim3(NB), dim3(256), 0, stream>>>(sm_buf, w1, b1, w2, b2, y_buf);
    k_scale<<<dim3(32, 16, NB), dim3(256), 0, stream>>>(x, y_buf, o32, o32t, sig_t);
    // fused gemm1 + attention (independent): 512 + 4096 blocks, 36 KB dynamic LDS
    k_gemm1_attn<<<dim3(4608), dim3(256), 36864, stream>>>(gusbf, o32, gbuf2, sig_t, o32t, g2b);
    k_tr<<<dim3(32, 32, NB), dim3(256), 0, stream>>>(gbuf2, g2b, catT);
    // Z[o,s] = sum_i dw[o,i] * catT[s,i] : M=512, N=1024, K=1024
    gemm_bt<float><<<dim3(8, 4, NB), dim3(256), 0, stream>>>(
        dwbf, catT, Z, 512, 1024, 1024, 0L, (long)NS * 1024, (long)NC * NS);
    k_norm<<<dim3(NB * NC), dim3(256), 0, stream>>>(Z, out);
}

// Round 5
// 220.858 us; speedup vs baseline: 1.0710x; 1.0710x over previous
//
#include <hip/hip_runtime.h>
#include <stdint.h>

#define NB 16
#define NC 512
#define NS 1024
#define NR 32

typedef unsigned short u16;
typedef unsigned int u32;

typedef __attribute__((ext_vector_type(8))) short short8;
typedef __attribute__((ext_vector_type(4))) float f32x4;

__device__ __forceinline__ float bf2f(u16 u) {
    union { u32 i; float f; } c; c.i = ((u32)u) << 16; return c.f;
}
__device__ __forceinline__ u16 f2bf(float f) {
    union { float f; u32 i; } c; c.f = f;
    u32 r = (c.i + 0x7FFFu + ((c.i >> 16) & 1u)) >> 16;
    return (u16)r;
}
__device__ __forceinline__ float sigm(float x) {
    return 1.0f / (1.0f + __expf(-x));
}

// ------- fused: spatial mean (blocks 0..8191) + bf16 convert (8192..12287)
__global__ void k_mean_cvt(const float* __restrict__ x, float* __restrict__ sm,
                           const float* __restrict__ g, const float* __restrict__ dw,
                           u16* __restrict__ gb, u16* __restrict__ dwb) {
    const int t = threadIdx.x;                  // 256
    if (blockIdx.x < NB * NC) {
        const int row = blockIdx.x;             // b*NC + c
        const float4* xr = (const float4*)(x + (long)row * NS);
        float4 v = xr[t];
        float p = v.x + v.y + v.z + v.w;
        for (int off = 32; off; off >>= 1) p += __shfl_down(p, off);
        __shared__ float red[4];
        if ((t & 63) == 0) red[t >> 6] = p;
        __syncthreads();
        if (t == 0) sm[row] = (red[0] + red[1] + red[2] + red[3]) * (1.0f / 1024.0f);
    } else {
        const int i = (blockIdx.x - NB * NC) * 256 + t;
        gb[i] = f2bf(g[i]);                      // 4096 blocks => exactly 1048576
        if (i < 524288) dwb[i] = f2bf(dw[i]);
    }
}

// ---------------- SE MLP: y = sigmoid(relu(s W1^T + b1) W2^T + b2) ------
__global__ void k_se(const float* __restrict__ sm, const float* __restrict__ w1,
                     const float* __restrict__ b1, const float* __restrict__ w2,
                     const float* __restrict__ b2, float* __restrict__ y) {
    const int b = blockIdx.x;
    __shared__ float s_s[NC];
    __shared__ float s_y1[NR];
    const int t = threadIdx.x;                  // 256
    s_s[t] = sm[b * NC + t];
    s_s[t + 256] = sm[b * NC + t + 256];
    __syncthreads();
    if (t < NR) {
        float acc = b1[t];
        for (int c = 0; c < NC; ++c) acc += s_s[c] * w1[t * NC + c];
        s_y1[t] = fmaxf(acc, 0.0f);
    }
    __syncthreads();
    for (int i = 0; i < 2; ++i) {
        int c = t + i * 256;
        float acc = b2[c];
#pragma unroll
        for (int r = 0; r < NR; ++r) acc += s_y1[r] * w2[c * NR + r];
        y[b * NC + c] = 1.0f / (1.0f + expf(-acc));
    }
}

// out32 = x*y -> bf16 [c,s] (o32), [s,c] (o32t), and sigmoid in [s,c] (sig_t)
__global__ void k_scale(const float* __restrict__ x, const float* __restrict__ y,
                        u16* __restrict__ o32, u16* __restrict__ o32t,
                        u16* __restrict__ sig_t) {
    const int b = blockIdx.z;
    const int c0 = blockIdx.y * 32;
    const int s0 = blockIdx.x * 32;
    const int tx = threadIdx.x & 31, ty = threadIdx.x >> 5;  // 32 x 8
    __shared__ float tile[32][33];
    const float* xb = x + (long)b * NC * NS;
#pragma unroll
    for (int it = 0; it < 4; ++it) {
        int c = c0 + ty + it * 8;
        float v = xb[(long)c * NS + s0 + tx] * y[b * NC + c];
        tile[ty + it * 8][tx] = v;
        o32[((long)b * NC + c) * NS + s0 + tx] = f2bf(v);
    }
    __syncthreads();
#pragma unroll
    for (int it = 0; it < 4; ++it) {
        int sr = ty + it * 8;
        float tv = tile[tx][sr];
        long idx = ((long)b * NS + (s0 + sr)) * NC + c0 + tx;
        o32t[idx] = f2bf(tv);
        sig_t[idx] = f2bf(sigm(tv));
    }
}

// ------- bf16 MFMA GEMM: C[m,n] = sum_k A[m,k]*Bt[n,k], 128x128 tile ----
// LDS layout XOR-swizzled: row r's 16B granule g stored at slot g^(r&7).
// Staging keeps lane-contiguous LDS dest; the GLOBAL source granule is permuted.
__device__ __forceinline__ void st_out(float* p, float v) { *p = v; }
__device__ __forceinline__ void st_out(u16* p, float v) { *p = f2bf(v); }

template <typename OT>
__global__ __launch_bounds__(256)
void gemm_bt(const u16* __restrict__ A, const u16* __restrict__ Bt, OT* __restrict__ Co,
             int M, int N, int K, long batA, long batB, long batC) {
    const int b = blockIdx.z;
    const u16* Ab = A + (long)b * batA;
    const u16* Bb = Bt + (long)b * batB;
    OT* Cb = Co + (long)b * batC;
    const int m0 = blockIdx.y * 128, n0 = blockIdx.x * 128;
    __shared__ __align__(16) u16 As[128 * 64];
    __shared__ __align__(16) u16 Bs[128 * 64];
    const int tid = threadIdx.x;
    const int lane = tid & 63, wave = tid >> 6;
    const int wm = (wave >> 1) * 64, wn = (wave & 1) * 64;
    f32x4 acc[4][4];
#pragma unroll
    for (int i = 0; i < 4; ++i)
#pragma unroll
        for (int j = 0; j < 4; ++j) acc[i][j] = (f32x4){0.f, 0.f, 0.f, 0.f};

    // staging: lane l -> row (wave*32 + q*8 + (l>>3)), source granule (l&7)^(l>>3)
    const int srow = lane >> 3;                 // 0..7
    const int sgr = (lane & 7) ^ srow;          // swizzled source granule
    const int ldsoff = lane * 8;                // element offset within q-chunk

    for (int k0 = 0; k0 < K; k0 += 64) {
#pragma unroll
        for (int q = 0; q < 4; ++q) {
            const int rl = wave * 32 + q * 8 + srow;
            const u16* ga = Ab + (long)(m0 + rl) * K + (k0 + sgr * 8);
            __builtin_amdgcn_global_load_lds(
                (const __attribute__((address_space(1))) u32*)ga,
                (__attribute__((address_space(3))) u32*)&As[wave * 2048 + q * 512 + ldsoff], 16, 0, 0);
            const u16* gb = Bb + (long)(n0 + rl) * K + (k0 + sgr * 8);
            __builtin_amdgcn_global_load_lds(
                (const __attribute__((address_space(1))) u32*)gb,
                (__attribute__((address_space(3))) u32*)&Bs[wave * 2048 + q * 512 + ldsoff], 16, 0, 0);
        }
        __syncthreads();
#pragma unroll
        for (int kk = 0; kk < 64; kk += 32) {
            const int gq = (kk >> 3) + (lane >> 4);     // logical granule 0..7
            const int slot = gq ^ (lane & 7);           // swizzled LDS slot
            short8 af[4], bfr[4];
#pragma unroll
            for (int i = 0; i < 4; ++i)
                af[i] = *(const short8*)&As[(wm + i * 16 + (lane & 15)) * 64 + slot * 8];
#pragma unroll
            for (int j = 0; j < 4; ++j)
                bfr[j] = *(const short8*)&Bs[(wn + j * 16 + (lane & 15)) * 64 + slot * 8];
#pragma unroll
            for (int i = 0; i < 4; ++i)
#pragma unroll
                for (int j = 0; j < 4; ++j)
                    acc[i][j] = __builtin_amdgcn_mfma_f32_16x16x32_bf16(af[i], bfr[j], acc[i][j], 0, 0, 0);
        }
        __syncthreads();
    }
    const int col = lane & 15, rq = (lane >> 4) * 4;
#pragma unroll
    for (int i = 0; i < 4; ++i)
#pragma unroll
        for (int j = 0; j < 4; ++j)
#pragma unroll
            for (int r = 0; r < 4; ++r) {
                int row = m0 + wm + i * 16 + rq + r;
                int ncol = n0 + wn + j * 16 + col;
                st_out(&Cb[(long)row * N + ncol], acc[i][j][r]);
            }
}

// ------- patch attention: block = 4 consecutive x at fixed y; LDS-shared rows
__global__ __launch_bounds__(256)
void k_attn(const u16* __restrict__ sig_t, const u16* __restrict__ o32t,
            u16* __restrict__ g2) {
    const int wave = threadIdx.x >> 6, lane = threadIdx.x & 63;
    const int tid = threadIdx.x;
    const int bx = blockIdx.x;                   // 256 blocks: 8 per row y
    const int b = blockIdx.y;
    const int y0 = bx >> 3;
    const int xbase = (bx & 7) * 4;
    const long base = (long)b * NS * NC;
    __shared__ __align__(16) u16 smem[2 * 18 * NC];   // [arr][pair][ch], 36 KB

#pragma unroll
    for (int r = 0; r < 9; ++r) {
        int idx = r * 256 + tid;
        int pair = idx >> 7;                      // 0..17
        int rem = idx & 127;
        int arr = rem >> 6;                       // 0=sig, 1=raw
        int ch0 = (rem & 63) * 8;
        int yy = y0 + pair / 6 - 1;
        int xx = xbase + pair % 6 - 1;
        short8 v;
        if (yy >= 0 && yy < 32 && xx >= 0 && xx < 32) {
            long roff = base + (long)(yy * 32 + xx) * NC + ch0;
            v = arr ? *(const short8*)&o32t[roff] : *(const short8*)&sig_t[roff];
        } else {
            v = (short8){0, 0, 0, 0, 0, 0, 0, 0};
        }
        *(short8*)&smem[(arr * 18 + pair) * NC + ch0] = v;
    }
    __syncthreads();

    const int coff = lane * 8;
    short8 csv = *(const short8*)&smem[(6 + wave + 1) * NC + coff];
    float sc[8];
#pragma unroll
    for (int j = 0; j < 8; ++j) sc[j] = bf2f((u16)csv[j]);

    float part[9];
#pragma unroll
    for (int k = 0; k < 9; ++k) {
        int pair = (k / 3) * 6 + wave + k % 3;
        short8 sv = *(const short8*)&smem[pair * NC + coff];
        float p = 0.f;
#pragma unroll
        for (int j = 0; j < 8; ++j) p += sc[j] * bf2f((u16)sv[j]);
        part[k] = p;
    }
#pragma unroll
    for (int k = 0; k < 9; ++k)
        for (int off = 32; off; off >>= 1) part[k] += __shfl_down(part[k], off);

    if (lane == 0) {
        float mx = -1e30f;
#pragma unroll
        for (int k = 0; k < 9; ++k) { part[k] *= (1.0f / 512.0f); mx = fmaxf(mx, part[k]); }
        float sum = 0.f;
#pragma unroll
        for (int k = 0; k < 9; ++k) { part[k] = __expf(part[k] - mx); sum += part[k]; }
        float inv = 1.0f / sum;
#pragma unroll
        for (int k = 0; k < 9; ++k) part[k] *= inv;
    }
    float g[8] = {0.f, 0.f, 0.f, 0.f, 0.f, 0.f, 0.f, 0.f};
#pragma unroll
    for (int k = 0; k < 9; ++k) {
        float a = __shfl(part[k], 0);
        int pair = (k / 3) * 6 + wave + k % 3;
        short8 rv = *(const short8*)&smem[(18 + pair) * NC + coff];
#pragma unroll
        for (int j = 0; j < 8; ++j) g[j] += a * bf2f((u16)rv[j]);
    }
    short8 ov;
#pragma unroll
    for (int j = 0; j < 8; ++j) ov[j] = (short)f2bf(g[j]);
    const int s = y0 * 32 + xbase + wave;
    *(short8*)&g2[base + (long)s * NC + coff] = ov;
}

// ------- catT[b][s][i] = cat[b][i][s]  (i<512: gbuf flat, else g2 flat) --
__global__ void k_tr(const u16* __restrict__ g, const u16* __restrict__ g2,
                     u16* __restrict__ ct) {
    const int b = blockIdx.z;
    const int i0 = blockIdx.y * 32, s0 = blockIdx.x * 32;
    const int tx = threadIdx.x & 31, ty = threadIdx.x >> 5;
    __shared__ u16 tile[32][33];
    const u16* src = (i0 < 512) ? (g + (long)b * 524288 + (long)i0 * 1024)
                                : (g2 + (long)b * 524288 + (long)(i0 - 512) * 1024);
#pragma unroll
    for (int it = 0; it < 4; ++it) {
        int il = ty + it * 8;
        tile[il][tx] = src[(long)il * 1024 + s0 + tx];
    }
    __syncthreads();
#pragma unroll
    for (int it = 0; it < 4; ++it) {
        int sl = ty + it * 8;
        ct[(long)b * 1048576 + (long)(s0 + sl) * 1024 + i0 + tx] = tile[tx][sl];
    }
}

// -------- InstanceNorm over s (1024) + LeakyReLU(0.2), per (b,o) row -----
__global__ void k_norm(const float* __restrict__ z, float* __restrict__ out) {
    const int row = blockIdx.x;                 // b*NC + o
    const float4* zr = (const float4*)(z + (long)row * NS);
    const int t = threadIdx.x;
    float4 v = zr[t];
    float sm = v.x + v.y + v.z + v.w;
    float sq = v.x * v.x + v.y * v.y + v.z * v.z + v.w * v.w;
    for (int off = 32; off; off >>= 1) { sm += __shfl_down(sm, off); sq += __shfl_down(sq, off); }
    __shared__ float rs[4], rq2[4];
    if ((t & 63) == 0) { rs[t >> 6] = sm; rq2[t >> 6] = sq; }
    __syncthreads();
    float tot = rs[0] + rs[1] + rs[2] + rs[3];
    float totq = rq2[0] + rq2[1] + rq2[2] + rq2[3];
    float mu = tot * (1.0f / 1024.0f);
    float var = totq * (1.0f / 1024.0f) - mu * mu;
    float sc = rsqrtf(var + 1e-5f);
    float4 o;
    float a;
    a = (v.x - mu) * sc; o.x = (a >= 0.f) ? a : 0.2f * a;
    a = (v.y - mu) * sc; o.y = (a >= 0.f) ? a : 0.2f * a;
    a = (v.z - mu) * sc; o.z = (a >= 0.f) ? a : 0.2f * a;
    a = (v.w - mu) * sc; o.w = (a >= 0.f) ? a : 0.2f * a;
    ((float4*)(out + (long)row * NS))[t] = o;
}

extern "C" void kernel_launch(void* const* d_in, const int* in_sizes, int n_in,
                              void* d_out, int out_size, void* d_ws, size_t ws_size,
                              hipStream_t stream) {
    const float* x   = (const float*)d_in[0];
    const float* w1  = (const float*)d_in[1];
    const float* b1  = (const float*)d_in[2];
    const float* w2  = (const float*)d_in[3];
    const float* b2  = (const float*)d_in[4];
    const float* dw  = (const float*)d_in[5];
    const float* gus = (const float*)d_in[6];
    float* out = (float*)d_out;
    char* ws = (char*)d_ws;

    // workspace layout (67.1 MB, region A/B overlays)
    float* sm_buf = (float*)(ws + 0);                    // 32 KB
    float* y_buf  = (float*)(ws + 32768);                // 32 KB
    u16* gusbf    = (u16*)(ws + 65536);                  // 2 MB
    u16* dwbf     = (u16*)(ws + 2162688);                // 1 MB
    char* regA    = ws + 3211264;                        // 32 MB region A
    u16* o32      = (u16*)regA;                          //   out32 bf16 [b][c][s]
    u16* o32t     = (u16*)(regA + 16777216);             //   out32 bf16 [b][s][c]
    u16* catT     = (u16*)regA;                          //   reuse A: catT [b][s][i]
    char* regB    = ws + 36765696;                       // 32 MB region B
    u16* sig_t    = (u16*)regB;                          //   sigmoid(out32) [b][s][c] (dies before gemm1)
    u16* gbuf     = (u16*)regB;                          //   gus_out flat bf16 (after attn)
    u16* g2b      = (u16*)(regB + 16777216);             //   out_csa flat bf16
    float* Z      = (float*)regB;                        //   reuse B: z fp32

    k_mean_cvt<<<dim3(NB * NC + 4096), dim3(256), 0, stream>>>(x, sm_buf, gus, dw, gusbf, dwbf);
    k_se<<<dim3(NB), dim3(256), 0, stream>>>(sm_buf, w1, b1, w2, b2, y_buf);
    k_scale<<<dim3(32, 16, NB), dim3(256), 0, stream>>>(x, y_buf, o32, o32t, sig_t);
    // attention first: sig_t (regB slot 0) dies here, then gemm1 writes gbuf there
    k_attn<<<dim3(256, NB), dim3(256), 0, stream>>>(sig_t, o32t, g2b);
    // G[p,ch] = sum_s gus[p,s] * out32[ch,s] : M=1024, N=512, K=1024
    gemm_bt<u16><<<dim3(4, 8, NB), dim3(256), 0, stream>>>(
        gusbf, o32, gbuf, 1024, 512, 1024, 0L, (long)NC * NS, (long)NC * NS);
    k_tr<<<dim3(32, 32, NB), dim3(256), 0, stream>>>(gbuf, g2b, catT);
    // Z[o,s] = sum_i dw[o,i] * catT[s,i] : M=512, N=1024, K=1024
    gemm_bt<float><<<dim3(8, 4, NB), dim3(256), 0, stream>>>(
        dwbf, catT, Z, 512, 1024, 1024, 0L, (long)NS * 1024, (long)NC * NS);
    k_norm<<<dim3(NB * NC), dim3(256), 0, stream>>>(Z, out);
}

// Round 6
// 214.572 us; speedup vs baseline: 1.1023x; 1.0293x over previous
//
#include <hip/hip_runtime.h>
#include <stdint.h>

#define NB 16
#define NC 512
#define NS 1024
#define NR 32

typedef unsigned short u16;
typedef unsigned int u32;

typedef __attribute__((ext_vector_type(8))) short short8;
typedef __attribute__((ext_vector_type(4))) float f32x4;

__device__ __forceinline__ float bf2f(u16 u) {
    union { u32 i; float f; } c; c.i = ((u32)u) << 16; return c.f;
}
__device__ __forceinline__ u16 f2bf(float f) {
    union { float f; u32 i; } c; c.f = f;
    u32 r = (c.i + 0x7FFFu + ((c.i >> 16) & 1u)) >> 16;
    return (u16)r;
}
__device__ __forceinline__ float sigm(float x) {
    return 1.0f / (1.0f + __expf(-x));
}

// ------- fused: spatial mean (blocks 0..8191) + bf16 convert (8192..12287)
__global__ void k_mean_cvt(const float* __restrict__ x, float* __restrict__ sm,
                           const float* __restrict__ g, const float* __restrict__ dw,
                           u16* __restrict__ gb, u16* __restrict__ dwb) {
    const int t = threadIdx.x;                  // 256
    if (blockIdx.x < NB * NC) {
        const int row = blockIdx.x;             // b*NC + c
        const float4* xr = (const float4*)(x + (long)row * NS);
        float4 v = xr[t];
        float p = v.x + v.y + v.z + v.w;
        for (int off = 32; off; off >>= 1) p += __shfl_down(p, off);
        __shared__ float red[4];
        if ((t & 63) == 0) red[t >> 6] = p;
        __syncthreads();
        if (t == 0) sm[row] = (red[0] + red[1] + red[2] + red[3]) * (1.0f / 1024.0f);
    } else {
        const int i = (blockIdx.x - NB * NC) * 256 + t;
        gb[i] = f2bf(g[i]);                      // 4096 blocks => exactly 1048576
        if (i < 524288) dwb[i] = f2bf(dw[i]);
    }
}

// ---------------- SE MLP: y = sigmoid(relu(s W1^T + b1) W2^T + b2) ------
__global__ void k_se(const float* __restrict__ sm, const float* __restrict__ w1,
                     const float* __restrict__ b1, const float* __restrict__ w2,
                     const float* __restrict__ b2, float* __restrict__ y) {
    const int b = blockIdx.x;
    __shared__ float s_s[NC];
    __shared__ float s_y1[NR];
    const int t = threadIdx.x;                  // 256
    s_s[t] = sm[b * NC + t];
    s_s[t + 256] = sm[b * NC + t + 256];
    __syncthreads();
    if (t < NR) {
        float acc = b1[t];
        for (int c = 0; c < NC; ++c) acc += s_s[c] * w1[t * NC + c];
        s_y1[t] = fmaxf(acc, 0.0f);
    }
    __syncthreads();
    for (int i = 0; i < 2; ++i) {
        int c = t + i * 256;
        float acc = b2[c];
#pragma unroll
        for (int r = 0; r < NR; ++r) acc += s_y1[r] * w2[c * NR + r];
        y[b * NC + c] = 1.0f / (1.0f + expf(-acc));
    }
}

// out32 = x*y -> bf16 [c,s] (o32), [s,c] (o32t), and sigmoid in [s,c] (sig_t)
__global__ void k_scale(const float* __restrict__ x, const float* __restrict__ y,
                        u16* __restrict__ o32, u16* __restrict__ o32t,
                        u16* __restrict__ sig_t) {
    const int b = blockIdx.z;
    const int c0 = blockIdx.y * 32;
    const int s0 = blockIdx.x * 32;
    const int tx = threadIdx.x & 31, ty = threadIdx.x >> 5;  // 32 x 8
    __shared__ float tile[32][33];
    const float* xb = x + (long)b * NC * NS;
#pragma unroll
    for (int it = 0; it < 4; ++it) {
        int c = c0 + ty + it * 8;
        float v = xb[(long)c * NS + s0 + tx] * y[b * NC + c];
        tile[ty + it * 8][tx] = v;
        o32[((long)b * NC + c) * NS + s0 + tx] = f2bf(v);
    }
    __syncthreads();
#pragma unroll
    for (int it = 0; it < 4; ++it) {
        int sr = ty + it * 8;
        float tv = tile[tx][sr];
        long idx = ((long)b * NS + (s0 + sr)) * NC + c0 + tx;
        o32t[idx] = f2bf(tv);
        sig_t[idx] = f2bf(sigm(tv));
    }
}

// ------- bf16 MFMA GEMM: C[m,n] = sum_k A[m,k]*Bt[n,k], 128x128 tile ----
// LDS layout XOR-swizzled: row r's 16B granule g stored at slot g^(r&7).
__device__ __forceinline__ void st_out(float* p, float v) { *p = v; }
__device__ __forceinline__ void st_out(u16* p, float v) { *p = f2bf(v); }

template <typename OT>
__global__ __launch_bounds__(256)
void gemm_bt(const u16* __restrict__ A, const u16* __restrict__ Bt, OT* __restrict__ Co,
             int M, int N, int K, long batA, long batB, long batC) {
    const int b = blockIdx.z;
    const u16* Ab = A + (long)b * batA;
    const u16* Bb = Bt + (long)b * batB;
    OT* Cb = Co + (long)b * batC;
    const int m0 = blockIdx.y * 128, n0 = blockIdx.x * 128;
    __shared__ __align__(16) u16 As[128 * 64];
    __shared__ __align__(16) u16 Bs[128 * 64];
    const int tid = threadIdx.x;
    const int lane = tid & 63, wave = tid >> 6;
    const int wm = (wave >> 1) * 64, wn = (wave & 1) * 64;
    f32x4 acc[4][4];
#pragma unroll
    for (int i = 0; i < 4; ++i)
#pragma unroll
        for (int j = 0; j < 4; ++j) acc[i][j] = (f32x4){0.f, 0.f, 0.f, 0.f};

    // staging: lane l -> row (wave*32 + q*8 + (l>>3)), source granule (l&7)^(l>>3)
    const int srow = lane >> 3;                 // 0..7
    const int sgr = (lane & 7) ^ srow;          // swizzled source granule
    const int ldsoff = lane * 8;                // element offset within q-chunk

    for (int k0 = 0; k0 < K; k0 += 64) {
#pragma unroll
        for (int q = 0; q < 4; ++q) {
            const int rl = wave * 32 + q * 8 + srow;
            const u16* ga = Ab + (long)(m0 + rl) * K + (k0 + sgr * 8);
            __builtin_amdgcn_global_load_lds(
                (const __attribute__((address_space(1))) u32*)ga,
                (__attribute__((address_space(3))) u32*)&As[wave * 2048 + q * 512 + ldsoff], 16, 0, 0);
            const u16* gb = Bb + (long)(n0 + rl) * K + (k0 + sgr * 8);
            __builtin_amdgcn_global_load_lds(
                (const __attribute__((address_space(1))) u32*)gb,
                (__attribute__((address_space(3))) u32*)&Bs[wave * 2048 + q * 512 + ldsoff], 16, 0, 0);
        }
        __syncthreads();
#pragma unroll
        for (int kk = 0; kk < 64; kk += 32) {
            const int gq = (kk >> 3) + (lane >> 4);     // logical granule 0..7
            const int slot = gq ^ (lane & 7);           // swizzled LDS slot
            short8 af[4], bfr[4];
#pragma unroll
            for (int i = 0; i < 4; ++i)
                af[i] = *(const short8*)&As[(wm + i * 16 + (lane & 15)) * 64 + slot * 8];
#pragma unroll
            for (int j = 0; j < 4; ++j)
                bfr[j] = *(const short8*)&Bs[(wn + j * 16 + (lane & 15)) * 64 + slot * 8];
#pragma unroll
            for (int i = 0; i < 4; ++i)
#pragma unroll
                for (int j = 0; j < 4; ++j)
                    acc[i][j] = __builtin_amdgcn_mfma_f32_16x16x32_bf16(af[i], bfr[j], acc[i][j], 0, 0, 0);
        }
        __syncthreads();
    }
    const int col = lane & 15, rq = (lane >> 4) * 4;
#pragma unroll
    for (int i = 0; i < 4; ++i)
#pragma unroll
        for (int j = 0; j < 4; ++j)
#pragma unroll
            for (int r = 0; r < 4; ++r) {
                int row = m0 + wm + i * 16 + rq + r;
                int ncol = n0 + wn + j * 16 + col;
                st_out(&Cb[(long)row * N + ncol], acc[i][j][r]);
            }
}

// ------- patch attention: block = 4 consecutive x at fixed y; LDS-shared rows
__global__ __launch_bounds__(256)
void k_attn(const u16* __restrict__ sig_t, const u16* __restrict__ o32t,
            u16* __restrict__ g2) {
    const int wave = threadIdx.x >> 6, lane = threadIdx.x & 63;
    const int tid = threadIdx.x;
    const int bx = blockIdx.x;                   // 256 blocks: 8 per row y
    const int b = blockIdx.y;
    const int y0 = bx >> 3;
    const int xbase = (bx & 7) * 4;
    const long base = (long)b * NS * NC;
    __shared__ __align__(16) u16 smem[2 * 18 * NC];   // [arr][pair][ch], 36 KB

#pragma unroll
    for (int r = 0; r < 9; ++r) {
        int idx = r * 256 + tid;
        int pair = idx >> 7;                      // 0..17
        int rem = idx & 127;
        int arr = rem >> 6;                       // 0=sig, 1=raw
        int ch0 = (rem & 63) * 8;
        int yy = y0 + pair / 6 - 1;
        int xx = xbase + pair % 6 - 1;
        short8 v;
        if (yy >= 0 && yy < 32 && xx >= 0 && xx < 32) {
            long roff = base + (long)(yy * 32 + xx) * NC + ch0;
            v = arr ? *(const short8*)&o32t[roff] : *(const short8*)&sig_t[roff];
        } else {
            v = (short8){0, 0, 0, 0, 0, 0, 0, 0};
        }
        *(short8*)&smem[(arr * 18 + pair) * NC + ch0] = v;
    }
    __syncthreads();

    const int coff = lane * 8;
    short8 csv = *(const short8*)&smem[(6 + wave + 1) * NC + coff];
    float sc[8];
#pragma unroll
    for (int j = 0; j < 8; ++j) sc[j] = bf2f((u16)csv[j]);

    float part[9];
#pragma unroll
    for (int k = 0; k < 9; ++k) {
        int pair = (k / 3) * 6 + wave + k % 3;
        short8 sv = *(const short8*)&smem[pair * NC + coff];
        float p = 0.f;
#pragma unroll
        for (int j = 0; j < 8; ++j) p += sc[j] * bf2f((u16)sv[j]);
        part[k] = p;
    }
#pragma unroll
    for (int k = 0; k < 9; ++k)
        for (int off = 32; off; off >>= 1) part[k] += __shfl_down(part[k], off);

    if (lane == 0) {
        float mx = -1e30f;
#pragma unroll
        for (int k = 0; k < 9; ++k) { part[k] *= (1.0f / 512.0f); mx = fmaxf(mx, part[k]); }
        float sum = 0.f;
#pragma unroll
        for (int k = 0; k < 9; ++k) { part[k] = __expf(part[k] - mx); sum += part[k]; }
        float inv = 1.0f / sum;
#pragma unroll
        for (int k = 0; k < 9; ++k) part[k] *= inv;
    }
    float g[8] = {0.f, 0.f, 0.f, 0.f, 0.f, 0.f, 0.f, 0.f};
#pragma unroll
    for (int k = 0; k < 9; ++k) {
        float a = __shfl(part[k], 0);
        int pair = (k / 3) * 6 + wave + k % 3;
        short8 rv = *(const short8*)&smem[(18 + pair) * NC + coff];
#pragma unroll
        for (int j = 0; j < 8; ++j) g[j] += a * bf2f((u16)rv[j]);
    }
    short8 ov;
#pragma unroll
    for (int j = 0; j < 8; ++j) ov[j] = (short)f2bf(g[j]);
    const int s = y0 * 32 + xbase + wave;
    *(short8*)&g2[base + (long)s * NC + coff] = ov;
}

// ------- catT[b][s][i] = cat[b][i][s], vectorized 64x64 tile transpose ---
// LDS granule-swizzle: input chunk (i, sg) stored at slot sg ^ ((i>>3)&7).
__global__ __launch_bounds__(256)
void k_tr(const u16* __restrict__ g, const u16* __restrict__ g2,
          u16* __restrict__ ct) {
    const int b = blockIdx.z;
    const int i0 = blockIdx.y * 64, s0 = blockIdx.x * 64;
    const int t = threadIdx.x;
    __shared__ __align__(16) u16 tile[64 * 64];       // 8 KB
    const u16* src = (i0 < 512) ? (g + (long)b * 524288 + (long)i0 * 1024)
                                : (g2 + (long)b * 524288 + (long)(i0 - 512) * 1024);
    // input: 512 short8 chunks; chunk c -> row i = c>>3, s-granule sg = c&7
#pragma unroll
    for (int it = 0; it < 2; ++it) {
        int c = it * 256 + t;
        int i = c >> 3, sg = c & 7;
        short8 v = *(const short8*)&src[(long)i * 1024 + s0 + sg * 8];
        int slot = sg ^ ((i >> 3) & 7);
        *(short8*)&tile[i * 64 + slot * 8] = v;
    }
    __syncthreads();
    // output: 512 short8 chunks; chunk c -> s-row = c>>3, i-granule ig = c&7
#pragma unroll
    for (int it = 0; it < 2; ++it) {
        int c = it * 256 + t;
        int srow = c >> 3, ig = c & 7;
        const int gs = srow >> 3, so = srow & 7;
        short8 v;
#pragma unroll
        for (int j = 0; j < 8; ++j) {
            int i = ig * 8 + j;
            int slot = gs ^ ig;                        // (i>>3)&7 == ig
            v[j] = (short)tile[i * 64 + slot * 8 + so];
        }
        *(short8*)&ct[(long)b * 1048576 + (long)(s0 + srow) * 1024 + i0 + ig * 8] = v;
    }
}

// -- InstanceNorm over s (1024) + LeakyReLU(0.2), per (b,o) row, bf16 in --
__global__ void k_norm(const u16* __restrict__ z, float* __restrict__ out) {
    const int row = blockIdx.x;                 // b*NC + o
    const int t = threadIdx.x;                  // 256, 4 elems each
    uint2 u = ((const uint2*)(z + (long)row * NS))[t];
    float v0 = bf2f((u16)(u.x & 0xffffu)), v1 = bf2f((u16)(u.x >> 16));
    float v2 = bf2f((u16)(u.y & 0xffffu)), v3 = bf2f((u16)(u.y >> 16));
    float sm = v0 + v1 + v2 + v3;
    float sq = v0 * v0 + v1 * v1 + v2 * v2 + v3 * v3;
    for (int off = 32; off; off >>= 1) { sm += __shfl_down(sm, off); sq += __shfl_down(sq, off); }
    __shared__ float rs[4], rq2[4];
    if ((t & 63) == 0) { rs[t >> 6] = sm; rq2[t >> 6] = sq; }
    __syncthreads();
    float tot = rs[0] + rs[1] + rs[2] + rs[3];
    float totq = rq2[0] + rq2[1] + rq2[2] + rq2[3];
    float mu = tot * (1.0f / 1024.0f);
    float var = totq * (1.0f / 1024.0f) - mu * mu;
    float sc = rsqrtf(var + 1e-5f);
    float4 o;
    float a;
    a = (v0 - mu) * sc; o.x = (a >= 0.f) ? a : 0.2f * a;
    a = (v1 - mu) * sc; o.y = (a >= 0.f) ? a : 0.2f * a;
    a = (v2 - mu) * sc; o.z = (a >= 0.f) ? a : 0.2f * a;
    a = (v3 - mu) * sc; o.w = (a >= 0.f) ? a : 0.2f * a;
    ((float4*)(out + (long)row * NS))[t] = o;
}

extern "C" void kernel_launch(void* const* d_in, const int* in_sizes, int n_in,
                              void* d_out, int out_size, void* d_ws, size_t ws_size,
                              hipStream_t stream) {
    const float* x   = (const float*)d_in[0];
    const float* w1  = (const float*)d_in[1];
    const float* b1  = (const float*)d_in[2];
    const float* w2  = (const float*)d_in[3];
    const float* b2  = (const float*)d_in[4];
    const float* dw  = (const float*)d_in[5];
    const float* gus = (const float*)d_in[6];
    float* out = (float*)d_out;
    char* ws = (char*)d_ws;

    // workspace layout (region A/B overlays)
    float* sm_buf = (float*)(ws + 0);                    // 32 KB
    float* y_buf  = (float*)(ws + 32768);                // 32 KB
    u16* gusbf    = (u16*)(ws + 65536);                  // 2 MB
    u16* dwbf     = (u16*)(ws + 2162688);                // 1 MB
    char* regA    = ws + 3211264;                        // 32 MB region A
    u16* o32      = (u16*)regA;                          //   out32 bf16 [b][c][s]
    u16* o32t     = (u16*)(regA + 16777216);             //   out32 bf16 [b][s][c]
    u16* catT     = (u16*)regA;                          //   reuse A: catT [b][s][i]
    char* regB    = ws + 36765696;                       // 32 MB region B
    u16* sig_t    = (u16*)regB;                          //   sigmoid(out32) [b][s][c] (dies before gemm1)
    u16* gbuf     = (u16*)regB;                          //   gus_out flat bf16 (after attn)
    u16* g2b      = (u16*)(regB + 16777216);             //   out_csa flat bf16
    u16* Z        = (u16*)regB;                          //   reuse B: z bf16 (33.5 MB)

    k_mean_cvt<<<dim3(NB * NC + 4096), dim3(256), 0, stream>>>(x, sm_buf, gus, dw, gusbf, dwbf);
    k_se<<<dim3(NB), dim3(256), 0, stream>>>(sm_buf, w1, b1, w2, b2, y_buf);
    k_scale<<<dim3(32, 16, NB), dim3(256), 0, stream>>>(x, y_buf, o32, o32t, sig_t);
    // attention first: sig_t (regB slot 0) dies here, then gemm1 writes gbuf there
    k_attn<<<dim3(256, NB), dim3(256), 0, stream>>>(sig_t, o32t, g2b);
    // G[p,ch] = sum_s gus[p,s] * out32[ch,s] : M=1024, N=512, K=1024
    gemm_bt<u16><<<dim3(4, 8, NB), dim3(256), 0, stream>>>(
        gusbf, o32, gbuf, 1024, 512, 1024, 0L, (long)NC * NS, (long)NC * NS);
    k_tr<<<dim3(16, 16, NB), dim3(256), 0, stream>>>(gbuf, g2b, catT);
    // Z[o,s] = sum_i dw[o,i] * catT[s,i] : M=512, N=1024, K=1024, bf16 out
    gemm_bt<u16><<<dim3(8, 4, NB), dim3(256), 0, stream>>>(
        dwbf, catT, Z, 512, 1024, 1024, 0L, (long)NS * 1024, (long)NC * NS);
    k_norm<<<dim3(NB * NC), dim3(256), 0, stream>>>(Z, out);
}

// Round 7
// 209.260 us; speedup vs baseline: 1.1303x; 1.0254x over previous
//
#include <hip/hip_runtime.h>
#include <stdint.h>

#define NB 16
#define NC 512
#define NS 1024
#define NR 32

typedef unsigned short u16;
typedef unsigned int u32;

typedef __attribute__((ext_vector_type(8))) short short8;
typedef __attribute__((ext_vector_type(4))) float f32x4;

__device__ __forceinline__ float bf2f(u16 u) {
    union { u32 i; float f; } c; c.i = ((u32)u) << 16; return c.f;
}
__device__ __forceinline__ u16 f2bf(float f) {
    union { float f; u32 i; } c; c.f = f;
    u32 r = (c.i + 0x7FFFu + ((c.i >> 16) & 1u)) >> 16;
    return (u16)r;
}
__device__ __forceinline__ float sigm(float x) {
    return 1.0f / (1.0f + __expf(-x));
}

// ------- fused: spatial mean (blocks 0..8191) + bf16 convert (8192..12287)
__global__ void k_mean_cvt(const float* __restrict__ x, float* __restrict__ sm,
                           const float* __restrict__ g, const float* __restrict__ dw,
                           u16* __restrict__ gb, u16* __restrict__ dwb) {
    const int t = threadIdx.x;                  // 256
    if (blockIdx.x < NB * NC) {
        const int row = blockIdx.x;             // b*NC + c
        const float4* xr = (const float4*)(x + (long)row * NS);
        float4 v = xr[t];
        float p = v.x + v.y + v.z + v.w;
        for (int off = 32; off; off >>= 1) p += __shfl_down(p, off);
        __shared__ float red[4];
        if ((t & 63) == 0) red[t >> 6] = p;
        __syncthreads();
        if (t == 0) sm[row] = (red[0] + red[1] + red[2] + red[3]) * (1.0f / 1024.0f);
    } else {
        const int i = (blockIdx.x - NB * NC) * 256 + t;
        gb[i] = f2bf(g[i]);                      // 4096 blocks => exactly 1048576
        if (i < 524288) dwb[i] = f2bf(dw[i]);
    }
}

// ---------------- SE MLP: y = sigmoid(relu(s W1^T + b1) W2^T + b2) ------
__global__ void k_se(const float* __restrict__ sm, const float* __restrict__ w1,
                     const float* __restrict__ b1, const float* __restrict__ w2,
                     const float* __restrict__ b2, float* __restrict__ y) {
    const int b = blockIdx.x;
    __shared__ float s_s[NC];
    __shared__ float s_y1[NR];
    const int t = threadIdx.x;                  // 256
    s_s[t] = sm[b * NC + t];
    s_s[t + 256] = sm[b * NC + t + 256];
    __syncthreads();
    if (t < NR) {
        float acc = b1[t];
        for (int c = 0; c < NC; ++c) acc += s_s[c] * w1[t * NC + c];
        s_y1[t] = fmaxf(acc, 0.0f);
    }
    __syncthreads();
    for (int i = 0; i < 2; ++i) {
        int c = t + i * 256;
        float acc = b2[c];
#pragma unroll
        for (int r = 0; r < NR; ++r) acc += s_y1[r] * w2[c * NR + r];
        y[b * NC + c] = 1.0f / (1.0f + expf(-acc));
    }
}

// out32 = x*y -> bf16 [c,s] (o32), [s,c] (o32t), and sigmoid in [s,c] (sig_t)
__global__ void k_scale(const float* __restrict__ x, const float* __restrict__ y,
                        u16* __restrict__ o32, u16* __restrict__ o32t,
                        u16* __restrict__ sig_t) {
    const int b = blockIdx.z;
    const int c0 = blockIdx.y * 32;
    const int s0 = blockIdx.x * 32;
    const int tx = threadIdx.x & 31, ty = threadIdx.x >> 5;  // 32 x 8
    __shared__ float tile[32][33];
    const float* xb = x + (long)b * NC * NS;
#pragma unroll
    for (int it = 0; it < 4; ++it) {
        int c = c0 + ty + it * 8;
        float v = xb[(long)c * NS + s0 + tx] * y[b * NC + c];
        tile[ty + it * 8][tx] = v;
        o32[((long)b * NC + c) * NS + s0 + tx] = f2bf(v);
    }
    __syncthreads();
#pragma unroll
    for (int it = 0; it < 4; ++it) {
        int sr = ty + it * 8;
        float tv = tile[tx][sr];
        long idx = ((long)b * NS + (s0 + sr)) * NC + c0 + tx;
        o32t[idx] = f2bf(tv);
        sig_t[idx] = f2bf(sigm(tv));
    }
}

// ------- bf16 MFMA GEMM: C[m,n] = sum_k A[m,k]*Bt[n,k], 128x128 tile ----
// BK=128 (half the barrier drains vs BK=64). LDS 64 KB, 2 blocks/CU (grid-
// limited anyway). XOR swizzle: row r's 16B granule g stored at slot g^(r&15).
__device__ __forceinline__ void st_out(float* p, float v) { *p = v; }
__device__ __forceinline__ void st_out(u16* p, float v) { *p = f2bf(v); }

template <typename OT>
__global__ __launch_bounds__(256)
void gemm_bt(const u16* __restrict__ A, const u16* __restrict__ Bt, OT* __restrict__ Co,
             int M, int N, int K, long batA, long batB, long batC) {
    const int b = blockIdx.z;
    const u16* Ab = A + (long)b * batA;
    const u16* Bb = Bt + (long)b * batB;
    OT* Cb = Co + (long)b * batC;
    const int m0 = blockIdx.y * 128, n0 = blockIdx.x * 128;
    __shared__ __align__(16) u16 As[128 * 128];   // 32 KB
    __shared__ __align__(16) u16 Bs[128 * 128];   // 32 KB
    const int tid = threadIdx.x;
    const int lane = tid & 63, wave = tid >> 6;
    const int wm = (wave >> 1) * 64, wn = (wave & 1) * 64;
    f32x4 acc[4][4];
#pragma unroll
    for (int i = 0; i < 4; ++i)
#pragma unroll
        for (int j = 0; j < 4; ++j) acc[i][j] = (f32x4){0.f, 0.f, 0.f, 0.f};

    // staging: 2048 chunks of 16B per operand; chunk c -> row c>>4, slot c&15,
    // source granule (c&15) ^ (row&15)
    int srow[8], sg8[8];
#pragma unroll
    for (int r = 0; r < 8; ++r) {
        int c = r * 256 + tid;
        srow[r] = c >> 4;
        sg8[r] = ((c & 15) ^ (srow[r] & 15)) * 8;
    }

    for (int k0 = 0; k0 < K; k0 += 128) {
#pragma unroll
        for (int r = 0; r < 8; ++r) {
            const int c = r * 256 + tid;
            const u16* ga = Ab + (long)(m0 + srow[r]) * K + (k0 + sg8[r]);
            __builtin_amdgcn_global_load_lds(
                (const __attribute__((address_space(1))) u32*)ga,
                (__attribute__((address_space(3))) u32*)&As[c * 8], 16, 0, 0);
            const u16* gb = Bb + (long)(n0 + srow[r]) * K + (k0 + sg8[r]);
            __builtin_amdgcn_global_load_lds(
                (const __attribute__((address_space(1))) u32*)gb,
                (__attribute__((address_space(3))) u32*)&Bs[c * 8], 16, 0, 0);
        }
        __syncthreads();
#pragma unroll
        for (int kk = 0; kk < 128; kk += 32) {
            const int gq = (kk >> 3) + (lane >> 4);     // logical granule 0..15
            const int slot = gq ^ (lane & 15);          // swizzled LDS slot
            short8 af[4], bfr[4];
#pragma unroll
            for (int i = 0; i < 4; ++i)
                af[i] = *(const short8*)&As[(wm + i * 16 + (lane & 15)) * 128 + slot * 8];
#pragma unroll
            for (int j = 0; j < 4; ++j)
                bfr[j] = *(const short8*)&Bs[(wn + j * 16 + (lane & 15)) * 128 + slot * 8];
#pragma unroll
            for (int i = 0; i < 4; ++i)
#pragma unroll
                for (int j = 0; j < 4; ++j)
                    acc[i][j] = __builtin_amdgcn_mfma_f32_16x16x32_bf16(af[i], bfr[j], acc[i][j], 0, 0, 0);
        }
        __syncthreads();
    }
    const int col = lane & 15, rq = (lane >> 4) * 4;
#pragma unroll
    for (int i = 0; i < 4; ++i)
#pragma unroll
        for (int j = 0; j < 4; ++j)
#pragma unroll
            for (int r = 0; r < 4; ++r) {
                int row = m0 + wm + i * 16 + rq + r;
                int ncol = n0 + wn + j * 16 + col;
                st_out(&Cb[(long)row * N + ncol], acc[i][j][r]);
            }
}

// ------- patch attention: block = 4 consecutive x at fixed y; LDS-shared rows
__global__ __launch_bounds__(256)
void k_attn(const u16* __restrict__ sig_t, const u16* __restrict__ o32t,
            u16* __restrict__ g2) {
    const int wave = threadIdx.x >> 6, lane = threadIdx.x & 63;
    const int tid = threadIdx.x;
    const int bx = blockIdx.x;                   // 256 blocks: 8 per row y
    const int b = blockIdx.y;
    const int y0 = bx >> 3;
    const int xbase = (bx & 7) * 4;
    const long base = (long)b * NS * NC;
    __shared__ __align__(16) u16 smem[2 * 18 * NC];   // [arr][pair][ch], 36 KB

#pragma unroll
    for (int r = 0; r < 9; ++r) {
        int idx = r * 256 + tid;
        int pair = idx >> 7;                      // 0..17
        int rem = idx & 127;
        int arr = rem >> 6;                       // 0=sig, 1=raw
        int ch0 = (rem & 63) * 8;
        int yy = y0 + pair / 6 - 1;
        int xx = xbase + pair % 6 - 1;
        short8 v;
        if (yy >= 0 && yy < 32 && xx >= 0 && xx < 32) {
            long roff = base + (long)(yy * 32 + xx) * NC + ch0;
            v = arr ? *(const short8*)&o32t[roff] : *(const short8*)&sig_t[roff];
        } else {
            v = (short8){0, 0, 0, 0, 0, 0, 0, 0};
        }
        *(short8*)&smem[(arr * 18 + pair) * NC + ch0] = v;
    }
    __syncthreads();

    const int coff = lane * 8;
    short8 csv = *(const short8*)&smem[(6 + wave + 1) * NC + coff];
    float sc[8];
#pragma unroll
    for (int j = 0; j < 8; ++j) sc[j] = bf2f((u16)csv[j]);

    float part[9];
#pragma unroll
    for (int k = 0; k < 9; ++k) {
        int pair = (k / 3) * 6 + wave + k % 3;
        short8 sv = *(const short8*)&smem[pair * NC + coff];
        float p = 0.f;
#pragma unroll
        for (int j = 0; j < 8; ++j) p += sc[j] * bf2f((u16)sv[j]);
        part[k] = p;
    }
#pragma unroll
    for (int k = 0; k < 9; ++k)
        for (int off = 32; off; off >>= 1) part[k] += __shfl_down(part[k], off);

    if (lane == 0) {
        float mx = -1e30f;
#pragma unroll
        for (int k = 0; k < 9; ++k) { part[k] *= (1.0f / 512.0f); mx = fmaxf(mx, part[k]); }
        float sum = 0.f;
#pragma unroll
        for (int k = 0; k < 9; ++k) { part[k] = __expf(part[k] - mx); sum += part[k]; }
        float inv = 1.0f / sum;
#pragma unroll
        for (int k = 0; k < 9; ++k) part[k] *= inv;
    }
    float g[8] = {0.f, 0.f, 0.f, 0.f, 0.f, 0.f, 0.f, 0.f};
#pragma unroll
    for (int k = 0; k < 9; ++k) {
        float a = __shfl(part[k], 0);
        int pair = (k / 3) * 6 + wave + k % 3;
        short8 rv = *(const short8*)&smem[(18 + pair) * NC + coff];
#pragma unroll
        for (int j = 0; j < 8; ++j) g[j] += a * bf2f((u16)rv[j]);
    }
    short8 ov;
#pragma unroll
    for (int j = 0; j < 8; ++j) ov[j] = (short)f2bf(g[j]);
    const int s = y0 * 32 + xbase + wave;
    *(short8*)&g2[base + (long)s * NC + coff] = ov;
}

// ------- catT[b][s][i] = cat[b][i][s], vectorized 64x64 tile transpose ---
// LDS granule-swizzle: input chunk (i, sg) stored at slot sg ^ ((i>>3)&7).
__global__ __launch_bounds__(256)
void k_tr(const u16* __restrict__ g, const u16* __restrict__ g2,
          u16* __restrict__ ct) {
    const int b = blockIdx.z;
    const int i0 = blockIdx.y * 64, s0 = blockIdx.x * 64;
    const int t = threadIdx.x;
    __shared__ __align__(16) u16 tile[64 * 64];       // 8 KB
    const u16* src = (i0 < 512) ? (g + (long)b * 524288 + (long)i0 * 1024)
                                : (g2 + (long)b * 524288 + (long)(i0 - 512) * 1024);
    // input: 512 short8 chunks; chunk c -> row i = c>>3, s-granule sg = c&7
#pragma unroll
    for (int it = 0; it < 2; ++it) {
        int c = it * 256 + t;
        int i = c >> 3, sg = c & 7;
        short8 v = *(const short8*)&src[(long)i * 1024 + s0 + sg * 8];
        int slot = sg ^ ((i >> 3) & 7);
        *(short8*)&tile[i * 64 + slot * 8] = v;
    }
    __syncthreads();
    // output: 512 short8 chunks; chunk c -> s-row = c>>3, i-granule ig = c&7
#pragma unroll
    for (int it = 0; it < 2; ++it) {
        int c = it * 256 + t;
        int srow = c >> 3, ig = c & 7;
        const int gs = srow >> 3, so = srow & 7;
        short8 v;
#pragma unroll
        for (int j = 0; j < 8; ++j) {
            int i = ig * 8 + j;
            int slot = gs ^ ig;                        // (i>>3)&7 == ig
            v[j] = (short)tile[i * 64 + slot * 8 + so];
        }
        *(short8*)&ct[(long)b * 1048576 + (long)(s0 + srow) * 1024 + i0 + ig * 8] = v;
    }
}

// -- InstanceNorm over s (1024) + LeakyReLU(0.2), per (b,o) row, bf16 in --
__global__ void k_norm(const u16* __restrict__ z, float* __restrict__ out) {
    const int row = blockIdx.x;                 // b*NC + o
    const int t = threadIdx.x;                  // 256, 4 elems each
    uint2 u = ((const uint2*)(z + (long)row * NS))[t];
    float v0 = bf2f((u16)(u.x & 0xffffu)), v1 = bf2f((u16)(u.x >> 16));
    float v2 = bf2f((u16)(u.y & 0xffffu)), v3 = bf2f((u16)(u.y >> 16));
    float sm = v0 + v1 + v2 + v3;
    float sq = v0 * v0 + v1 * v1 + v2 * v2 + v3 * v3;
    for (int off = 32; off; off >>= 1) { sm += __shfl_down(sm, off); sq += __shfl_down(sq, off); }
    __shared__ float rs[4], rq2[4];
    if ((t & 63) == 0) { rs[t >> 6] = sm; rq2[t >> 6] = sq; }
    __syncthreads();
    float tot = rs[0] + rs[1] + rs[2] + rs[3];
    float totq = rq2[0] + rq2[1] + rq2[2] + rq2[3];
    float mu = tot * (1.0f / 1024.0f);
    float var = totq * (1.0f / 1024.0f) - mu * mu;
    float sc = rsqrtf(var + 1e-5f);
    float4 o;
    float a;
    a = (v0 - mu) * sc; o.x = (a >= 0.f) ? a : 0.2f * a;
    a = (v1 - mu) * sc; o.y = (a >= 0.f) ? a : 0.2f * a;
    a = (v2 - mu) * sc; o.z = (a >= 0.f) ? a : 0.2f * a;
    a = (v3 - mu) * sc; o.w = (a >= 0.f) ? a : 0.2f * a;
    ((float4*)(out + (long)row * NS))[t] = o;
}

extern "C" void kernel_launch(void* const* d_in, const int* in_sizes, int n_in,
                              void* d_out, int out_size, void* d_ws, size_t ws_size,
                              hipStream_t stream) {
    const float* x   = (const float*)d_in[0];
    const float* w1  = (const float*)d_in[1];
    const float* b1  = (const float*)d_in[2];
    const float* w2  = (const float*)d_in[3];
    const float* b2  = (const float*)d_in[4];
    const float* dw  = (const float*)d_in[5];
    const float* gus = (const float*)d_in[6];
    float* out = (float*)d_out;
    char* ws = (char*)d_ws;

    // workspace layout (region A/B overlays)
    float* sm_buf = (float*)(ws + 0);                    // 32 KB
    float* y_buf  = (float*)(ws + 32768);                // 32 KB
    u16* gusbf    = (u16*)(ws + 65536);                  // 2 MB
    u16* dwbf     = (u16*)(ws + 2162688);                // 1 MB
    char* regA    = ws + 3211264;                        // 32 MB region A
    u16* o32      = (u16*)regA;                          //   out32 bf16 [b][c][s]
    u16* o32t     = (u16*)(regA + 16777216);             //   out32 bf16 [b][s][c]
    u16* catT     = (u16*)regA;                          //   reuse A: catT [b][s][i]
    char* regB    = ws + 36765696;                       // 32 MB region B
    u16* sig_t    = (u16*)regB;                          //   sigmoid(out32) [b][s][c] (dies before gemm1)
    u16* gbuf     = (u16*)regB;                          //   gus_out flat bf16 (after attn)
    u16* g2b      = (u16*)(regB + 16777216);             //   out_csa flat bf16
    u16* Z        = (u16*)regB;                          //   reuse B: z bf16 (33.5 MB)

    k_mean_cvt<<<dim3(NB * NC + 4096), dim3(256), 0, stream>>>(x, sm_buf, gus, dw, gusbf, dwbf);
    k_se<<<dim3(NB), dim3(256), 0, stream>>>(sm_buf, w1, b1, w2, b2, y_buf);
    k_scale<<<dim3(32, 16, NB), dim3(256), 0, stream>>>(x, y_buf, o32, o32t, sig_t);
    // attention first: sig_t (regB slot 0) dies here, then gemm1 writes gbuf there
    k_attn<<<dim3(256, NB), dim3(256), 0, stream>>>(sig_t, o32t, g2b);
    // G[p,ch] = sum_s gus[p,s] * out32[ch,s] : M=1024, N=512, K=1024
    gemm_bt<u16><<<dim3(4, 8, NB), dim3(256), 0, stream>>>(
        gusbf, o32, gbuf, 1024, 512, 1024, 0L, (long)NC * NS, (long)NC * NS);
    k_tr<<<dim3(16, 16, NB), dim3(256), 0, stream>>>(gbuf, g2b, catT);
    // Z[o,s] = sum_i dw[o,i] * catT[s,i] : M=512, N=1024, K=1024, bf16 out
    gemm_bt<u16><<<dim3(8, 4, NB), dim3(256), 0, stream>>>(
        dwbf, catT, Z, 512, 1024, 1024, 0L, (long)NS * 1024, (long)NC * NS);
    k_norm<<<dim3(NB * NC), dim3(256), 0, stream>>>(Z, out);
}

// Round 9
// 203.785 us; speedup vs baseline: 1.1607x; 1.0269x over previous
//
#include <hip/hip_runtime.h>
#include <stdint.h>

#define NB 16
#define NC 512
#define NS 1024
#define NR 32

typedef unsigned short u16;
typedef unsigned int u32;

typedef __attribute__((ext_vector_type(8))) short short8;
typedef __attribute__((ext_vector_type(4))) float f32x4;

__device__ __forceinline__ float bf2f(u16 u) {
    union { u32 i; float f; } c; c.i = ((u32)u) << 16; return c.f;
}
__device__ __forceinline__ u16 f2bf(float f) {
    union { float f; u32 i; } c; c.f = f;
    u32 r = (c.i + 0x7FFFu + ((c.i >> 16) & 1u)) >> 16;
    return (u16)r;
}
__device__ __forceinline__ float sigm(float x) {
    return 1.0f / (1.0f + __expf(-x));
}

// ------- fused: spatial mean (blocks 0..8191) + bf16 convert (8192..12287)
__global__ void k_mean_cvt(const float* __restrict__ x, float* __restrict__ sm,
                           const float* __restrict__ g, const float* __restrict__ dw,
                           u16* __restrict__ gb, u16* __restrict__ dwb) {
    const int t = threadIdx.x;                  // 256
    if (blockIdx.x < NB * NC) {
        const int row = blockIdx.x;             // b*NC + c
        const float4* xr = (const float4*)(x + (long)row * NS);
        float4 v = xr[t];
        float p = v.x + v.y + v.z + v.w;
        for (int off = 32; off; off >>= 1) p += __shfl_down(p, off);
        __shared__ float red[4];
        if ((t & 63) == 0) red[t >> 6] = p;
        __syncthreads();
        if (t == 0) sm[row] = (red[0] + red[1] + red[2] + red[3]) * (1.0f / 1024.0f);
    } else {
        const int i = (blockIdx.x - NB * NC) * 256 + t;
        gb[i] = f2bf(g[i]);                      // 4096 blocks => exactly 1048576
        if (i < 524288) dwb[i] = f2bf(dw[i]);
    }
}

// ---------------- SE MLP: y = sigmoid(relu(s W1^T + b1) W2^T + b2) ------
__global__ void k_se(const float* __restrict__ sm, const float* __restrict__ w1,
                     const float* __restrict__ b1, const float* __restrict__ w2,
                     const float* __restrict__ b2, float* __restrict__ y) {
    const int b = blockIdx.x;
    __shared__ float s_s[NC];
    __shared__ float s_y1[NR];
    const int t = threadIdx.x;                  // 256
    s_s[t] = sm[b * NC + t];
    s_s[t + 256] = sm[b * NC + t + 256];
    __syncthreads();
    if (t < NR) {
        float acc = b1[t];
        for (int c = 0; c < NC; ++c) acc += s_s[c] * w1[t * NC + c];
        s_y1[t] = fmaxf(acc, 0.0f);
    }
    __syncthreads();
    for (int i = 0; i < 2; ++i) {
        int c = t + i * 256;
        float acc = b2[c];
#pragma unroll
        for (int r = 0; r < NR; ++r) acc += s_y1[r] * w2[c * NR + r];
        y[b * NC + c] = 1.0f / (1.0f + expf(-acc));
    }
}

// out32 = x*y -> bf16 [c,s] (o32), [s,c] (o32t), and sigmoid in [s,c] (sig_t)
__global__ void k_scale(const float* __restrict__ x, const float* __restrict__ y,
                        u16* __restrict__ o32, u16* __restrict__ o32t,
                        u16* __restrict__ sig_t) {
    const int b = blockIdx.z;
    const int c0 = blockIdx.y * 32;
    const int s0 = blockIdx.x * 32;
    const int tx = threadIdx.x & 31, ty = threadIdx.x >> 5;  // 32 x 8
    __shared__ float tile[32][33];
    const float* xb = x + (long)b * NC * NS;
#pragma unroll
    for (int it = 0; it < 4; ++it) {
        int c = c0 + ty + it * 8;
        float v = xb[(long)c * NS + s0 + tx] * y[b * NC + c];
        tile[ty + it * 8][tx] = v;
        o32[((long)b * NC + c) * NS + s0 + tx] = f2bf(v);
    }
    __syncthreads();
#pragma unroll
    for (int it = 0; it < 4; ++it) {
        int sr = ty + it * 8;
        float tv = tile[tx][sr];
        long idx = ((long)b * NS + (s0 + sr)) * NC + c0 + tx;
        o32t[idx] = f2bf(tv);
        sig_t[idx] = f2bf(sigm(tv));
    }
}

// ------- bf16 MFMA GEMM: C[m,n] = sum_k A[m,k]*Bt[n,k], 128x128 tile ----
// BK=128. XOR swizzle: row r's 16B granule g stored at slot g^(r&15).
// BANDED mode (gemm1->catT): blockIdx.y = m-tile*2 + band; B global row =
// 2*n + band; C row offset band*512. Implements catT[q*512+r][i] =
// sum_k gus[2i+q][k] * o32[r][k] (torch-view reshape algebra).
__device__ __forceinline__ void st_out(float* p, float v) { *p = v; }
__device__ __forceinline__ void st_out(u16* p, float v) { *p = f2bf(v); }

template <typename OT, bool BANDED>
__global__ __launch_bounds__(256)
void gemm_bt(const u16* __restrict__ A, const u16* __restrict__ Bt, OT* __restrict__ Co,
             int M, int N, int K, long batA, long batB, long batC, int ldc) {
    const int b = blockIdx.z;
    const u16* Ab = A + (long)b * batA;
    const u16* Bb = Bt + (long)b * batB;
    OT* Cb = Co + (long)b * batC;
    int m0, band;
    if (BANDED) { band = blockIdx.y & 1; m0 = (blockIdx.y >> 1) * 128; }
    else        { band = 0; m0 = blockIdx.y * 128; }
    const int n0 = blockIdx.x * 128;
    __shared__ __align__(16) u16 As[128 * 128];   // 32 KB
    __shared__ __align__(16) u16 Bs[128 * 128];   // 32 KB
    const int tid = threadIdx.x;
    const int lane = tid & 63, wave = tid >> 6;
    const int wm = (wave >> 1) * 64, wn = (wave & 1) * 64;
    f32x4 acc[4][4];
#pragma unroll
    for (int i = 0; i < 4; ++i)
#pragma unroll
        for (int j = 0; j < 4; ++j) acc[i][j] = (f32x4){0.f, 0.f, 0.f, 0.f};

    // staging: 2048 chunks of 16B per operand; chunk c -> row c>>4, slot c&15,
    // source granule (c&15) ^ (row&15)
    int srow[8], sg8[8];
#pragma unroll
    for (int r = 0; r < 8; ++r) {
        int c = r * 256 + tid;
        srow[r] = c >> 4;
        sg8[r] = ((c & 15) ^ (srow[r] & 15)) * 8;
    }

    for (int k0 = 0; k0 < K; k0 += 128) {
#pragma unroll
        for (int r = 0; r < 8; ++r) {
            const int c = r * 256 + tid;
            const u16* ga = Ab + (long)(m0 + srow[r]) * K + (k0 + sg8[r]);
            __builtin_amdgcn_global_load_lds(
                (const __attribute__((address_space(1))) u32*)ga,
                (__attribute__((address_space(3))) u32*)&As[c * 8], 16, 0, 0);
            const int brow = BANDED ? (2 * (n0 + srow[r]) + band) : (n0 + srow[r]);
            const u16* gb = Bb + (long)brow * K + (k0 + sg8[r]);
            __builtin_amdgcn_global_load_lds(
                (const __attribute__((address_space(1))) u32*)gb,
                (__attribute__((address_space(3))) u32*)&Bs[c * 8], 16, 0, 0);
        }
        __syncthreads();
#pragma unroll
        for (int kk = 0; kk < 128; kk += 32) {
            const int gq = (kk >> 3) + (lane >> 4);     // logical granule 0..15
            const int slot = gq ^ (lane & 15);          // swizzled LDS slot
            short8 af[4], bfr[4];
#pragma unroll
            for (int i = 0; i < 4; ++i)
                af[i] = *(const short8*)&As[(wm + i * 16 + (lane & 15)) * 128 + slot * 8];
#pragma unroll
            for (int j = 0; j < 4; ++j)
                bfr[j] = *(const short8*)&Bs[(wn + j * 16 + (lane & 15)) * 128 + slot * 8];
#pragma unroll
            for (int i = 0; i < 4; ++i)
#pragma unroll
                for (int j = 0; j < 4; ++j)
                    acc[i][j] = __builtin_amdgcn_mfma_f32_16x16x32_bf16(af[i], bfr[j], acc[i][j], 0, 0, 0);
        }
        __syncthreads();
    }
    const int col = lane & 15, rq = (lane >> 4) * 4;
    const int crow0 = (BANDED ? band * 512 : 0) + m0 + wm;
#pragma unroll
    for (int i = 0; i < 4; ++i)
#pragma unroll
        for (int j = 0; j < 4; ++j)
#pragma unroll
            for (int r = 0; r < 4; ++r) {
                int row = crow0 + i * 16 + rq + r;
                int ncol = n0 + wn + j * 16 + col;
                st_out(&Cb[(long)row * ldc + ncol], acc[i][j][r]);
            }
}

// ------- patch attention: block = 4 consecutive x at fixed y; LDS-shared rows
__global__ __launch_bounds__(256)
void k_attn(const u16* __restrict__ sig_t, const u16* __restrict__ o32t,
            u16* __restrict__ g2) {
    const int wave = threadIdx.x >> 6, lane = threadIdx.x & 63;
    const int tid = threadIdx.x;
    const int bx = blockIdx.x;                   // 256 blocks: 8 per row y
    const int b = blockIdx.y;
    const int y0 = bx >> 3;
    const int xbase = (bx & 7) * 4;
    const long base = (long)b * NS * NC;
    __shared__ __align__(16) u16 smem[2 * 18 * NC];   // [arr][pair][ch], 36 KB

#pragma unroll
    for (int r = 0; r < 9; ++r) {
        int idx = r * 256 + tid;
        int pair = idx >> 7;                      // 0..17
        int rem = idx & 127;
        int arr = rem >> 6;                       // 0=sig, 1=raw
        int ch0 = (rem & 63) * 8;
        int yy = y0 + pair / 6 - 1;
        int xx = xbase + pair % 6 - 1;
        short8 v;
        if (yy >= 0 && yy < 32 && xx >= 0 && xx < 32) {
            long roff = base + (long)(yy * 32 + xx) * NC + ch0;
            v = arr ? *(const short8*)&o32t[roff] : *(const short8*)&sig_t[roff];
        } else {
            v = (short8){0, 0, 0, 0, 0, 0, 0, 0};
        }
        *(short8*)&smem[(arr * 18 + pair) * NC + ch0] = v;
    }
    __syncthreads();

    const int coff = lane * 8;
    short8 csv = *(const short8*)&smem[(6 + wave + 1) * NC + coff];
    float sc[8];
#pragma unroll
    for (int j = 0; j < 8; ++j) sc[j] = bf2f((u16)csv[j]);

    float part[9];
#pragma unroll
    for (int k = 0; k < 9; ++k) {
        int pair = (k / 3) * 6 + wave + k % 3;
        short8 sv = *(const short8*)&smem[pair * NC + coff];
        float p = 0.f;
#pragma unroll
        for (int j = 0; j < 8; ++j) p += sc[j] * bf2f((u16)sv[j]);
        part[k] = p;
    }
#pragma unroll
    for (int k = 0; k < 9; ++k)
        for (int off = 32; off; off >>= 1) part[k] += __shfl_down(part[k], off);

    if (lane == 0) {
        float mx = -1e30f;
#pragma unroll
        for (int k = 0; k < 9; ++k) { part[k] *= (1.0f / 512.0f); mx = fmaxf(mx, part[k]); }
        float sum = 0.f;
#pragma unroll
        for (int k = 0; k < 9; ++k) { part[k] = __expf(part[k] - mx); sum += part[k]; }
        float inv = 1.0f / sum;
#pragma unroll
        for (int k = 0; k < 9; ++k) part[k] *= inv;
    }
    float g[8] = {0.f, 0.f, 0.f, 0.f, 0.f, 0.f, 0.f, 0.f};
#pragma unroll
    for (int k = 0; k < 9; ++k) {
        float a = __shfl(part[k], 0);
        int pair = (k / 3) * 6 + wave + k % 3;
        short8 rv = *(const short8*)&smem[(18 + pair) * NC + coff];
#pragma unroll
        for (int j = 0; j < 8; ++j) g[j] += a * bf2f((u16)rv[j]);
    }
    short8 ov;
#pragma unroll
    for (int j = 0; j < 8; ++j) ov[j] = (short)f2bf(g[j]);
    const int s = y0 * 32 + xbase + wave;
    *(short8*)&g2[base + (long)s * NC + coff] = ov;
}

// ------- catT[b][s][512+i] = csa_flat[b][i*1024+s]  (g2 half only) ------
// LDS granule-swizzle: input chunk (i, sg) stored at slot sg ^ ((i>>3)&7).
__global__ __launch_bounds__(256)
void k_tr(const u16* __restrict__ g2, u16* __restrict__ ct) {
    const int b = blockIdx.z;
    const int i0 = blockIdx.y * 64, s0 = blockIdx.x * 64;   // i0 in [0,512)
    const int t = threadIdx.x;
    __shared__ __align__(16) u16 tile[64 * 64];       // 8 KB
    const u16* src = g2 + (long)b * 524288 + (long)i0 * 1024;
    // input: 512 short8 chunks; chunk c -> row i = c>>3, s-granule sg = c&7
#pragma unroll
    for (int it = 0; it < 2; ++it) {
        int c = it * 256 + t;
        int i = c >> 3, sg = c & 7;
        short8 v = *(const short8*)&src[(long)i * 1024 + s0 + sg * 8];
        int slot = sg ^ ((i >> 3) & 7);
        *(short8*)&tile[i * 64 + slot * 8] = v;
    }
    __syncthreads();
    // output: 512 short8 chunks; chunk c -> s-row = c>>3, i-granule ig = c&7
#pragma unroll
    for (int it = 0; it < 2; ++it) {
        int c = it * 256 + t;
        int srow = c >> 3, ig = c & 7;
        const int gs = srow >> 3, so = srow & 7;
        short8 v;
#pragma unroll
        for (int j = 0; j < 8; ++j) {
            int i = ig * 8 + j;
            int slot = gs ^ ig;                        // (i>>3)&7 == ig
            v[j] = (short)tile[i * 64 + slot * 8 + so];
        }
        *(short8*)&ct[(long)b * 1048576 + (long)(s0 + srow) * 1024 + 512 + i0 + ig * 8] = v;
    }
}

// -- InstanceNorm over s (1024) + LeakyReLU(0.2), per (b,o) row, bf16 in --
__global__ void k_norm(const u16* __restrict__ z, float* __restrict__ out) {
    const int row = blockIdx.x;                 // b*NC + o
    const int t = threadIdx.x;                  // 256, 4 elems each
    uint2 u = ((const uint2*)(z + (long)row * NS))[t];
    float v0 = bf2f((u16)(u.x & 0xffffu)), v1 = bf2f((u16)(u.x >> 16));
    float v2 = bf2f((u16)(u.y & 0xffffu)), v3 = bf2f((u16)(u.y >> 16));
    float sm = v0 + v1 + v2 + v3;
    float sq = v0 * v0 + v1 * v1 + v2 * v2 + v3 * v3;
    for (int off = 32; off; off >>= 1) { sm += __shfl_down(sm, off); sq += __shfl_down(sq, off); }
    __shared__ float rs[4], rq2[4];
    if ((t & 63) == 0) { rs[t >> 6] = sm; rq2[t >> 6] = sq; }
    __syncthreads();
    float tot = rs[0] + rs[1] + rs[2] + rs[3];
    float totq = rq2[0] + rq2[1] + rq2[2] + rq2[3];
    float mu = tot * (1.0f / 1024.0f);
    float var = totq * (1.0f / 1024.0f) - mu * mu;
    float sc = rsqrtf(var + 1e-5f);
    float4 o;
    float a;
    a = (v0 - mu) * sc; o.x = (a >= 0.f) ? a : 0.2f * a;
    a = (v1 - mu) * sc; o.y = (a >= 0.f) ? a : 0.2f * a;
    a = (v2 - mu) * sc; o.z = (a >= 0.f) ? a : 0.2f * a;
    a = (v3 - mu) * sc; o.w = (a >= 0.f) ? a : 0.2f * a;
    ((float4*)(out + (long)row * NS))[t] = o;
}

extern "C" void kernel_launch(void* const* d_in, const int* in_sizes, int n_in,
                              void* d_out, int out_size, void* d_ws, size_t ws_size,
                              hipStream_t stream) {
    const float* x   = (const float*)d_in[0];
    const float* w1  = (const float*)d_in[1];
    const float* b1  = (const float*)d_in[2];
    const float* w2  = (const float*)d_in[3];
    const float* b2  = (const float*)d_in[4];
    const float* dw  = (const float*)d_in[5];
    const float* gus = (const float*)d_in[6];
    float* out = (float*)d_out;
    char* ws = (char*)d_ws;

    // workspace layout, 70.3 MB total, sequential-overlay safe:
    //  head 3.2 MB | o32 16 MB | o32t 16 MB | sig_t 16 MB | g2b 16 MB
    //  catT (32 MB) = o32t+sig_t slots (both dead after attn)
    //  Z    (16 MB) = o32 slot (dead after gemm1)
    float* sm_buf = (float*)(ws + 0);                    // 32 KB
    float* y_buf  = (float*)(ws + 32768);                // 32 KB
    u16* gusbf    = (u16*)(ws + 65536);                  // 2 MB
    u16* dwbf     = (u16*)(ws + 2162688);                // 1 MB
    u16* o32      = (u16*)(ws + 3211264);                // 16 MB [c,s]
    u16* o32t     = (u16*)(ws + 19988480);               // 16 MB [s,c]
    u16* sig_t    = (u16*)(ws + 36765696);               // 16 MB [s,c]
    u16* g2b      = (u16*)(ws + 53542912);               // 16 MB csa flat
    u16* catT     = (u16*)(ws + 19988480);               // 32 MB (over o32t+sig_t)
    u16* Z        = (u16*)(ws + 3211264);                // 16 MB (over o32)

    k_mean_cvt<<<dim3(NB * NC + 4096), dim3(256), 0, stream>>>(x, sm_buf, gus, dw, gusbf, dwbf);
    k_se<<<dim3(NB), dim3(256), 0, stream>>>(sm_buf, w1, b1, w2, b2, y_buf);
    k_scale<<<dim3(32, 16, NB), dim3(256), 0, stream>>>(x, y_buf, o32, o32t, sig_t);
    // attn: reads sig_t+o32t, writes g2b. After this, o32t/sig_t are dead.
    k_attn<<<dim3(256, NB), dim3(256), 0, stream>>>(sig_t, o32t, g2b);
    // gemm1 (banded): catT[q*512+r][i] = sum_k gus[2i+q][k]*o32[r][k]
    // reads o32 [3.2,20.0) MB, writes catT [20.0,53.5) MB - disjoint.
    gemm_bt<u16, true><<<dim3(4, 8, NB), dim3(256), 0, stream>>>(
        o32, gusbf, catT, 512, 512, 1024, (long)NC * NS, 0L, (long)NS * 1024, 1024);
    // transpose g2 half into catT columns 512..1023 (g2b dies here)
    k_tr<<<dim3(16, 8, NB), dim3(256), 0, stream>>>(g2b, catT);
    // gemm2: Z[o,s] = sum_i dw[o,i]*catT[s,i]; Z over o32 (dead) - disjoint from catT.
    gemm_bt<u16, false><<<dim3(8, 4, NB), dim3(256), 0, stream>>>(
        dwbf, catT, Z, 512, 1024, 1024, 0L, (long)NS * 1024, (long)NC * NS, 1024);
    k_norm<<<dim3(NB * NC), dim3(256), 0, stream>>>(Z, out);
}